// Round 1
// baseline (243.485 us; speedup 1.0000x reference)
//
#include <hip/hip_runtime.h>
#include <hip/hip_bf16.h>

typedef __attribute__((ext_vector_type(8))) short short8;
typedef __attribute__((ext_vector_type(4))) float f32x4;

// ---------------- gamma = mean(|W|) + 1e-6, deterministic two-stage ----------------

__global__ void kabs_partial(const float* __restrict__ W, double* __restrict__ part, int n) {
    __shared__ double sd[256];
    const int tid = threadIdx.x;
    double s = 0.0;
    for (int i = blockIdx.x * blockDim.x + tid; i < n; i += gridDim.x * blockDim.x)
        s += (double)fabsf(W[i]);
    sd[tid] = s;
    __syncthreads();
    for (int off = 128; off > 0; off >>= 1) {
        if (tid < off) sd[tid] += sd[tid + off];
        __syncthreads();
    }
    if (tid == 0) part[blockIdx.x] = sd[0];
}

__global__ void kgamma(const double* __restrict__ part, float* __restrict__ gout, int nelem) {
    __shared__ double sd[256];
    const int tid = threadIdx.x;
    double s = part[tid] + part[tid + 256] + part[tid + 512] + part[tid + 768];
    sd[tid] = s;
    __syncthreads();
    for (int off = 128; off > 0; off >>= 1) {
        if (tid < off) sd[tid] += sd[tid + off];
        __syncthreads();
    }
    if (tid == 0) gout[0] = (float)(sd[0] / (double)nelem) + 1e-6f;
}

// ---------------- quantizers: write bf16 {-1,0,+1} bit patterns ----------------

__device__ __forceinline__ unsigned int qw_h(float w, float g) {
    // replicate: round(|w|/g) (RNE) clamped to <=1, times sign(w)
    float t = fabsf(w) / g;
    unsigned int u = __float_as_uint(w);
    unsigned int h = 0x3F80u | ((u >> 16) & 0x8000u);   // +-1.0 bf16
    return (rintf(t) >= 1.0f) ? h : 0u;
}

__global__ void kquant_w(const float4* __restrict__ W4, unsigned short* __restrict__ Wq,
                         const float* __restrict__ gptr, int n4) {
    int i = blockIdx.x * blockDim.x + threadIdx.x;
    if (i >= n4) return;
    const float g = *gptr;
    float4 w = W4[i];
    unsigned int h0 = qw_h(w.x, g) | (qw_h(w.y, g) << 16);
    unsigned int h1 = qw_h(w.z, g) | (qw_h(w.w, g) << 16);
    ((uint2*)Wq)[i] = make_uint2(h0, h1);
}

__device__ __forceinline__ unsigned int sgn_h(float a) {
    unsigned int u = __float_as_uint(a);
    return (u & 0x7FFFFFFFu) ? (0x3F80u | ((u >> 16) & 0x8000u)) : 0u;
}
__device__ __forceinline__ unsigned int sgn2(float a, float b) {
    return sgn_h(a) | (sgn_h(b) << 16);
}

__global__ void kquant_x(const float4* __restrict__ X4, uint4* __restrict__ Xq, size_t n8) {
    size_t i = (size_t)blockIdx.x * blockDim.x + threadIdx.x;
    if (i >= n8) return;
    float4 a = X4[2 * i], b = X4[2 * i + 1];
    uint4 o;
    o.x = sgn2(a.x, a.y);
    o.y = sgn2(a.z, a.w);
    o.z = sgn2(b.x, b.y);
    o.w = sgn2(b.z, b.w);
    Xq[i] = o;
}

// ---------------- bf16 MFMA GEMM: C[M][N] = A[M][K] * B[N][K]^T ----------------
// m97-style: 128x128 tile, BK=64, 4 waves (each 64x64 = 4x4 fragments of 16x16x32),
// global_load_lds width=16 staging, linear LDS.

__global__ __launch_bounds__(256) void kgemm(const unsigned short* __restrict__ A,
                                             const unsigned short* __restrict__ B,
                                             float* __restrict__ C,
                                             int M, int N, int K) {
    __shared__ unsigned short As[128 * 64];
    __shared__ unsigned short Bs[128 * 64];
    const int tid = threadIdx.x;
    const int nbn = N >> 7;
    const int bm = blockIdx.x / nbn, bn = blockIdx.x % nbn;
    const int row0 = bm << 7, col0 = bn << 7;
    const int lane = tid & 63, wid = tid >> 6;
    const int wr = (wid >> 1) * 64, wc = (wid & 1) * 64;
    f32x4 acc[4][4] = {};

    const int trow = tid >> 3;        // 0..31: row within a 32-row staging chunk
    const int tcol = (tid & 7) * 8;   // element column (8 bf16 = 16B per lane)

    for (int k0 = 0; k0 < K; k0 += 64) {
#pragma unroll
        for (int i = 0; i < 4; ++i) {
            const int r = i * 32 + trow;
            const unsigned short* g = A + (size_t)(row0 + r) * K + k0 + tcol;
            __builtin_amdgcn_global_load_lds(
                (const __attribute__((address_space(1))) unsigned int*)g,
                (__attribute__((address_space(3))) unsigned int*)&As[r * 64 + tcol], 16, 0, 0);
        }
#pragma unroll
        for (int i = 0; i < 4; ++i) {
            const int r = i * 32 + trow;
            const unsigned short* g = B + (size_t)(col0 + r) * K + k0 + tcol;
            __builtin_amdgcn_global_load_lds(
                (const __attribute__((address_space(1))) unsigned int*)g,
                (__attribute__((address_space(3))) unsigned int*)&Bs[r * 64 + tcol], 16, 0, 0);
        }
        __syncthreads();   // drains vmcnt before LDS reads

        const int lr = lane & 15, lk = (lane >> 4) * 8;
#pragma unroll
        for (int ks = 0; ks < 2; ++ks) {
            short8 av[4], bv[4];
#pragma unroll
            for (int m = 0; m < 4; ++m)
                av[m] = *(const short8*)&As[(wr + m * 16 + lr) * 64 + ks * 32 + lk];
#pragma unroll
            for (int n = 0; n < 4; ++n)
                bv[n] = *(const short8*)&Bs[(wc + n * 16 + lr) * 64 + ks * 32 + lk];
#pragma unroll
            for (int m = 0; m < 4; ++m)
#pragma unroll
                for (int n = 0; n < 4; ++n)
                    acc[m][n] = __builtin_amdgcn_mfma_f32_16x16x32_bf16(av[m], bv[n], acc[m][n], 0, 0, 0);
        }
        __syncthreads();
    }

    // C/D layout (m89-verified): col = lane&15, row = (lane>>4)*4 + reg
    const int crow = (lane >> 4) * 4, ccol = lane & 15;
#pragma unroll
    for (int m = 0; m < 4; ++m) {
#pragma unroll
        for (int n = 0; n < 4; ++n) {
            float* cp = C + (size_t)(row0 + wr + m * 16 + crow) * N + (col0 + wc + n * 16 + ccol);
#pragma unroll
            for (int r = 0; r < 4; ++r)
                cp[(size_t)r * N] = acc[m][n][r];
        }
    }
}

// ---------------- correct-but-slow fallback if workspace is tiny ----------------

__global__ void knaive(const float* __restrict__ X, const float* __restrict__ W,
                       const float* __restrict__ gptr, float* __restrict__ out,
                       int N, int K) {
    size_t idx = (size_t)blockIdx.x * blockDim.x + threadIdx.x;
    const int m = (int)(idx / N), n = (int)(idx % N);
    const float g = *gptr;
    const float* xr = X + (size_t)m * K;
    const float* wrow = W + (size_t)n * K;
    float acc = 0.f;
    for (int k = 0; k < K; ++k) {
        float xv = xr[k];
        float xs = (xv > 0.f) ? 1.f : ((xv < 0.f) ? -1.f : 0.f);
        float w = wrow[k];
        float wq = (rintf(fabsf(w) / g) >= 1.f) ? ((w < 0.f) ? -1.f : 1.f) : 0.f;
        acc += xs * wq;
    }
    out[idx] = acc;
}

// ---------------- launch ----------------

extern "C" void kernel_launch(void* const* d_in, const int* in_sizes, int n_in,
                              void* d_out, int out_size, void* d_ws, size_t ws_size,
                              hipStream_t stream) {
    const float* x = (const float*)d_in[0];
    const float* W = (const float*)d_in[1];
    float* out = (float*)d_out;

    const int K = 2048;                 // in_features
    const int N = in_sizes[1] / K;      // out_features = 2048
    const int M = in_sizes[0] / K;      // 4*4096 = 16384
    const int nW = in_sizes[1];

    char* ws = (char*)d_ws;
    double* partials = (double*)ws;                       // 1024 doubles = 8 KB
    float* gamma = (float*)(ws + 8192);
    unsigned short* wq = (unsigned short*)(ws + 16384);
    unsigned short* xq = (unsigned short*)(ws + 16384 + (size_t)N * K * 2);
    const size_t need = 16384 + (size_t)N * K * 2 + (size_t)M * K * 2;

    kabs_partial<<<1024, 256, 0, stream>>>(W, partials, nW);
    kgamma<<<1, 256, 0, stream>>>(partials, gamma, nW);

    if (ws_size >= need) {
        kquant_w<<<nW / (256 * 4), 256, 0, stream>>>((const float4*)W, wq, gamma, nW / 4);
        const size_t n8 = (size_t)M * K / 8;
        kquant_x<<<(unsigned)(n8 / 256), 256, 0, stream>>>((const float4*)x, (uint4*)xq, n8);
        kgemm<<<(M / 128) * (N / 128), 256, 0, stream>>>(xq, wq, out, M, N, K);
    } else {
        knaive<<<(unsigned)((size_t)M * N / 256), 256, 0, stream>>>(x, W, gamma, out, N, K);
    }
}

// Round 2
// 181.605 us; speedup vs baseline: 1.3407x; 1.3407x over previous
//
#include <hip/hip_runtime.h>
#include <hip/hip_bf16.h>

typedef __attribute__((ext_vector_type(8))) short short8;
typedef __attribute__((ext_vector_type(4))) float f32x4;
typedef unsigned short ushort;

// ---------------- gamma = mean(|W|) + 1e-6, deterministic two-stage ----------------

__global__ void kabs_partial(const float* __restrict__ W, double* __restrict__ part, int n) {
    __shared__ double sd[256];
    const int tid = threadIdx.x;
    double s = 0.0;
    for (int i = blockIdx.x * blockDim.x + tid; i < n; i += gridDim.x * blockDim.x)
        s += (double)fabsf(W[i]);
    sd[tid] = s;
    __syncthreads();
    for (int off = 128; off > 0; off >>= 1) {
        if (tid < off) sd[tid] += sd[tid + off];
        __syncthreads();
    }
    if (tid == 0) part[blockIdx.x] = sd[0];
}

__global__ void kgamma(const double* __restrict__ part, float* __restrict__ gout, int nelem) {
    __shared__ double sd[256];
    const int tid = threadIdx.x;
    double s = part[tid] + part[tid + 256] + part[tid + 512] + part[tid + 768];
    sd[tid] = s;
    __syncthreads();
    for (int off = 128; off > 0; off >>= 1) {
        if (tid < off) sd[tid] += sd[tid + off];
        __syncthreads();
    }
    if (tid == 0) gout[0] = (float)(sd[0] / (double)nelem) + 1e-6f;
}

// ---------------- quantizers: write bf16 {-1,0,+1} bit patterns ----------------

__device__ __forceinline__ unsigned int qw_h(float w, float g) {
    float t = fabsf(w) / g;
    unsigned int u = __float_as_uint(w);
    unsigned int h = 0x3F80u | ((u >> 16) & 0x8000u);   // +-1.0 bf16
    return (rintf(t) >= 1.0f) ? h : 0u;
}

__global__ void kquant_w(const float4* __restrict__ W4, unsigned short* __restrict__ Wq,
                         const float* __restrict__ gptr, int n4) {
    int i = blockIdx.x * blockDim.x + threadIdx.x;
    if (i >= n4) return;
    const float g = *gptr;
    float4 w = W4[i];
    unsigned int h0 = qw_h(w.x, g) | (qw_h(w.y, g) << 16);
    unsigned int h1 = qw_h(w.z, g) | (qw_h(w.w, g) << 16);
    ((uint2*)Wq)[i] = make_uint2(h0, h1);
}

__device__ __forceinline__ unsigned int sgn_h(float a) {
    unsigned int u = __float_as_uint(a);
    return (u & 0x7FFFFFFFu) ? (0x3F80u | ((u >> 16) & 0x8000u)) : 0u;
}
__device__ __forceinline__ unsigned int sgn2(float a, float b) {
    return sgn_h(a) | (sgn_h(b) << 16);
}

__global__ void kquant_x(const float4* __restrict__ X4, uint4* __restrict__ Xq, size_t n8) {
    size_t i = (size_t)blockIdx.x * blockDim.x + threadIdx.x;
    if (i >= n8) return;
    float4 a = X4[2 * i], b = X4[2 * i + 1];
    uint4 o;
    o.x = sgn2(a.x, a.y);
    o.y = sgn2(a.z, a.w);
    o.z = sgn2(b.x, b.y);
    o.w = sgn2(b.z, b.w);
    Xq[i] = o;
}

// ---------------- 256x256 8-phase bf16 MFMA GEMM: C[M][N] = A[M][K] * B[N][K]^T --------
// 8 waves (2M x 4N), per-wave 128x64 output spanning both M-halves.
// LDS [dbuf][half][128][64] per operand (128 KiB total), T2 XOR-swizzle on reads with
// inverse pre-applied to global source (global_load_lds dest stays linear).
// 4 phases per K-tile: {ds_read frags | issue 1 half-tile of t+1 | counted vmcnt | barrier
//                       | setprio(1) 16xMFMA setprio(0) | barrier}.  vmcnt never 0 in loop.

#define STAGE_HALF(SRC, DST, BASE_ROW, KB)                                                  \
    {                                                                                       \
        _Pragma("unroll")                                                                   \
        for (int l = 0; l < 2; ++l) {                                                       \
            const int r_ = l * 64 + srow;                                                   \
            const ushort* g_ = (SRC) + (size_t)((BASE_ROW) + r_) * K + (KB) +               \
                               (sec ^ ((r_ & 7) << 3));                                     \
            __builtin_amdgcn_global_load_lds(                                               \
                (const __attribute__((address_space(1))) unsigned int*)g_,                  \
                (__attribute__((address_space(3))) unsigned int*)&(DST)[r_][sec], 16, 0, 0);\
        }                                                                                   \
    }

__global__ __launch_bounds__(512, 2) void kgemm(const ushort* __restrict__ A,
                                                const ushort* __restrict__ B,
                                                float* __restrict__ C,
                                                int M, int N, int K) {
    __shared__ ushort As[2][2][128][64];
    __shared__ ushort Bs[2][2][128][64];

    const int tid = threadIdx.x;
    const int lane = tid & 63;
    const int wid = tid >> 6;      // 0..7
    const int wm = wid >> 2;       // 0..1  (M sub-block within each half)
    const int wn = wid & 3;        // 0..3  (N sub-block)

    // T1: XCD-aware block swizzle (grid % 8 == 0 here)
    int bid = blockIdx.x;
    const int nwg = gridDim.x;
    if ((nwg & 7) == 0) bid = (bid & 7) * (nwg >> 3) + (bid >> 3);
    const int nbn = N >> 8;
    const int bm = bid / nbn, bn = bid % nbn;
    const int row0 = bm << 8, col0 = bn << 8;

    const int lr = lane & 15;
    const int lk = (lane >> 4) * 8;

    // staging thread mapping: 512 threads cover 64 rows x 64 cols per load instr
    const int srow = tid >> 3;          // 0..63
    const int sec  = (tid & 7) * 8;     // element chunk (8 bf16 = 16 B)

    f32x4 acc[8][4] = {};
    const int NT = K >> 6;

    // ---- prologue: stage tile 0 fully into dbuf 0, drain once
    STAGE_HALF(A, As[0][0], row0, 0);
    STAGE_HALF(B, Bs[0][0], col0, 0);
    STAGE_HALF(B, Bs[0][1], col0 + 128, 0);
    STAGE_HALF(A, As[0][1], row0 + 128, 0);
    asm volatile("s_waitcnt vmcnt(0)" ::: "memory");
    __builtin_amdgcn_s_barrier();
    asm volatile("" ::: "memory");

    int cur = 0;
    for (int t = 0; t < NT; ++t) {
        const int nxt = cur ^ 1;
        const int kb = (t + 1) << 6;
        const bool pf = (t + 1 < NT);
        short8 bv[4][2];

#pragma unroll
        for (int ph = 0; ph < 4; ++ph) {
            // ---- ds_read register subtile (phase 0 also loads all B frags)
            if (ph == 0) {
#pragma unroll
                for (int n = 0; n < 4; ++n) {
                    const int rb = (wn & 1) * 64 + n * 16 + lr;
#pragma unroll
                    for (int ks = 0; ks < 2; ++ks) {
                        const int e = ks * 32 + lk;
                        bv[n][ks] = *(const short8*)&Bs[cur][wn >> 1][rb][e ^ ((rb & 7) << 3)];
                    }
                }
            }
            short8 av[2][2];
#pragma unroll
            for (int mi = 0; mi < 2; ++mi) {
                const int m = ph * 2 + mi;
                const int ra = wm * 64 + (m & 3) * 16 + lr;
#pragma unroll
                for (int ks = 0; ks < 2; ++ks) {
                    const int e = ks * 32 + lk;
                    av[mi][ks] = *(const short8*)&As[cur][m >> 2][ra][e ^ ((ra & 7) << 3)];
                }
            }
            // ---- issue one half-tile of tile t+1 (order: Ah0, Bh0, Bh1, Ah1)
            if (pf) {
                if (ph == 0) STAGE_HALF(A, As[nxt][0], row0, kb);
                if (ph == 1) STAGE_HALF(B, Bs[nxt][0], col0, kb);
                if (ph == 2) STAGE_HALF(B, Bs[nxt][1], col0 + 128, kb);
                if (ph == 3) STAGE_HALF(A, As[nxt][1], row0 + 128, kb);
            }
            // ---- counted waits (never 0): ph1 guards Ah1(t) before ph2 reads it;
            //      ph3 guards Ah0/Bh0/Bh1(t+1) before next tile's ph0 reads them.
            if (ph == 1) asm volatile("s_waitcnt vmcnt(4)" ::: "memory");
            if (ph == 3) asm volatile("s_waitcnt vmcnt(2)" ::: "memory");
            asm volatile("" ::: "memory");
            __builtin_amdgcn_s_barrier();
            asm volatile("s_waitcnt lgkmcnt(0)" ::: "memory");
            __builtin_amdgcn_s_setprio(1);
#pragma unroll
            for (int mi = 0; mi < 2; ++mi)
#pragma unroll
                for (int n = 0; n < 4; ++n)
#pragma unroll
                    for (int ks = 0; ks < 2; ++ks)
                        acc[ph * 2 + mi][n] = __builtin_amdgcn_mfma_f32_16x16x32_bf16(
                            av[mi][ks], bv[n][ks], acc[ph * 2 + mi][n], 0, 0, 0);
            __builtin_amdgcn_s_setprio(0);
            asm volatile("" ::: "memory");
            __builtin_amdgcn_s_barrier();
            asm volatile("" ::: "memory");
        }
        cur = nxt;
    }

    // ---- epilogue: C/D layout col = lane&15, row = (lane>>4)*4 + reg (m89-verified)
#pragma unroll
    for (int m = 0; m < 8; ++m) {
        const int grow = row0 + (m >> 2) * 128 + wm * 64 + (m & 3) * 16 + (lane >> 4) * 4;
#pragma unroll
        for (int n = 0; n < 4; ++n) {
            float* cp = C + (size_t)grow * N + col0 + wn * 64 + n * 16 + (lane & 15);
#pragma unroll
            for (int r = 0; r < 4; ++r)
                cp[(size_t)r * N] = acc[m][n][r];
        }
    }
}

// ---------------- correct-but-slow fallback if workspace is tiny ----------------

__global__ void knaive(const float* __restrict__ X, const float* __restrict__ W,
                       const float* __restrict__ gptr, float* __restrict__ out,
                       int N, int K) {
    size_t idx = (size_t)blockIdx.x * blockDim.x + threadIdx.x;
    const int m = (int)(idx / N), n = (int)(idx % N);
    const float g = *gptr;
    const float* xr = X + (size_t)m * K;
    const float* wrow = W + (size_t)n * K;
    float acc = 0.f;
    for (int k = 0; k < K; ++k) {
        float xv = xr[k];
        float xs = (xv > 0.f) ? 1.f : ((xv < 0.f) ? -1.f : 0.f);
        float w = wrow[k];
        float wq = (rintf(fabsf(w) / g) >= 1.f) ? ((w < 0.f) ? -1.f : 1.f) : 0.f;
        acc += xs * wq;
    }
    out[idx] = acc;
}

// ---------------- launch ----------------

extern "C" void kernel_launch(void* const* d_in, const int* in_sizes, int n_in,
                              void* d_out, int out_size, void* d_ws, size_t ws_size,
                              hipStream_t stream) {
    const float* x = (const float*)d_in[0];
    const float* W = (const float*)d_in[1];
    float* out = (float*)d_out;

    const int K = 2048;                 // in_features
    const int N = in_sizes[1] / K;      // out_features = 2048
    const int M = in_sizes[0] / K;      // 4*4096 = 16384
    const int nW = in_sizes[1];

    char* ws = (char*)d_ws;
    double* partials = (double*)ws;                       // 1024 doubles = 8 KB
    float* gamma = (float*)(ws + 8192);
    ushort* wq = (ushort*)(ws + 16384);
    ushort* xq = (ushort*)(ws + 16384 + (size_t)N * K * 2);
    const size_t need = 16384 + (size_t)N * K * 2 + (size_t)M * K * 2;

    kabs_partial<<<1024, 256, 0, stream>>>(W, partials, nW);
    kgamma<<<1, 256, 0, stream>>>(partials, gamma, nW);

    if (ws_size >= need && (M % 256) == 0 && (N % 256) == 0 && (K % 64) == 0) {
        kquant_w<<<nW / (256 * 4), 256, 0, stream>>>((const float4*)W, wq, gamma, nW / 4);
        const size_t n8 = (size_t)M * K / 8;
        kquant_x<<<(unsigned)(n8 / 256), 256, 0, stream>>>((const float4*)x, (uint4*)xq, n8);
        kgemm<<<(M / 256) * (N / 256), 512, 0, stream>>>(xq, wq, out, M, N, K);
    } else {
        knaive<<<(unsigned)((size_t)M * N / 256), 256, 0, stream>>>(x, W, gamma, out, N, K);
    }
}